// Round 9
// baseline (152.935 us; speedup 1.0000x reference)
//
#include <hip/hip_runtime.h>

// DilatedSpatialAttention — round 9: conv restructured for memory parallelism.
// DTYPES (established rounds 0-2): inputs fp32, output fp32.
// R7->R8 delta (-10.0us, conv-only change) => conv is ~34us, NOT issue-bound:
// 4x fewer load insts bought only 1.3x. Revised theory: the 268MB ws-fill
// flushes L2+L3 every replay -> conv reads are cold HBM (~900cyc); R7 conv had
// VGPR=12 -> loads serialized through few regs -> ~1 outstanding/wave -> BW
// capped at ~1.9TB/s. Fix: 2 y-pixels/thread (share 2 of 3 dilated tap rows),
// ALL 24 float4 loads issued up-front into distinct regs (~24KB in flight per
// wave; 12 waves/CU covers the 2.4MB chip-wide latency-BW product).
// Attn kernel byte-identical to R8. absmax must stay exactly 1.220703e-4.
#define B_    16
#define HH    32
#define WW    32
#define CC    256
#define HEADS 8
#define HD    32
#define S_    1024
#define KT    128                 // keys per LDS tile
#define NITER (S_ / KT)           // 8
#define SCALE_L2E 0.25503486f     // 32^-0.5 * log2(e)  (pre-folded into Kws)

typedef unsigned short u16;
typedef unsigned int   u32;
typedef __attribute__((ext_vector_type(8))) short short8;  // 8 bf16 (A/B frag)
typedef __attribute__((ext_vector_type(4))) float f32x4;   // C/D frag

__device__ __forceinline__ u16 f2bf(float f) {             // RNE
    u32 x = __float_as_uint(f);
    return (u16)((x + 0x7fffu + ((x >> 16) & 1u)) >> 16);
}
__device__ __forceinline__ u32 pack2bf(float lo, float hi) {
    return (u32)f2bf(lo) | ((u32)f2bf(hi) << 16);
}

// ---------------------------------------------------------------------------
// Kernel 1: depthwise dilated 3x3 (dil=2, SAME) conv of key_in AND value
// (fp32 in), restaged head-major bf16: ws[(b*8+h)*1024 + s][d].
// K rows pre-scaled by SCALE_L2E (log2 domain for the attn exp2).
// One thread = 4 channels x 2 y-pixels (y0, y0+2); 24 float4 loads up-front.
// ---------------------------------------------------------------------------
__global__ __launch_bounds__(256) void dw_conv_kernel(
    const float* __restrict__ key_in, const float* __restrict__ value,
    const float* __restrict__ ck, const float* __restrict__ cb,
    u16* __restrict__ Kws, u16* __restrict__ Vws)
{
    int idx = blockIdx.x * 256 + threadIdx.x;  // (b, ypair, x, c4)
    int c4 = idx & 63;                         // 4-channel group
    int x  = (idx >> 6) & 31;
    int py = (idx >> 11) & 15;
    int b  = idx >> 15;
    int y0 = (py >> 1) * 4 + (py & 1);         // outputs y0 and y0+2

    const float4* K4 = (const float4*)key_in;  // [(b*32+y)*32+x]*64 + c4
    const float4* V4 = (const float4*)value;
    const float4 z4 = make_float4(0.f, 0.f, 0.f, 0.f);

    // ---- all taps up-front: 4 rows (y0-2,y0,y0+2,y0+4) x 3 cols, K and V ----
    float4 kk[4][3], vv[4][3];
    #pragma unroll
    for (int r = 0; r < 4; r++) {
        int yy = y0 - 2 + 2 * r;
        bool yok = (yy >= 0) && (yy < HH);
        #pragma unroll
        for (int ci = 0; ci < 3; ci++) {
            int xx = x - 2 + 2 * ci;
            bool ok = yok && (xx >= 0) && (xx < WW);
            size_t ii = ((((size_t)b * HH + yy) * WW) + xx) * 64 + c4;
            kk[r][ci] = ok ? K4[ii] : z4;
            vv[r][ci] = ok ? V4[ii] : z4;
        }
    }

    // ---- weights + bias (L1-resident after first wave) ----
    float4 w9[9];
    #pragma unroll
    for (int t = 0; t < 9; t++) w9[t] = *(const float4*)(ck + t * CC + 4 * c4);
    float4 bias4 = *(const float4*)(cb + 4 * c4);

    float4 kaA = bias4, vaA = bias4;           // output at y0
    float4 kaB = bias4, vaB = bias4;           // output at y0+2
    #pragma unroll
    for (int kh = 0; kh < 3; kh++) {
        #pragma unroll
        for (int kw = 0; kw < 3; kw++) {
            float4 w = w9[kh * 3 + kw];
            float4 a, v;
            a = kk[kh][kw];     kaA.x += w.x*a.x; kaA.y += w.y*a.y; kaA.z += w.z*a.z; kaA.w += w.w*a.w;
            v = vv[kh][kw];     vaA.x += w.x*v.x; vaA.y += w.y*v.y; vaA.z += w.z*v.z; vaA.w += w.w*v.w;
            a = kk[kh + 1][kw]; kaB.x += w.x*a.x; kaB.y += w.y*a.y; kaB.z += w.z*a.z; kaB.w += w.w*a.w;
            v = vv[kh + 1][kw]; vaB.x += w.x*v.x; vaB.y += w.y*v.y; vaB.z += w.z*v.z; vaB.w += w.w*v.w;
        }
    }

    int h = c4 >> 3;                 // (4*c4)>>5
    int d = (c4 & 7) * 4;            // (4*c4)&31
    size_t base = ((size_t)(b * HEADS + h)) * S_ * HD + d;
    size_t oA = base + (size_t)(y0 * WW + x) * HD;
    size_t oB = base + (size_t)((y0 + 2) * WW + x) * HD;
    *(uint2*)&Kws[oA] = make_uint2(pack2bf(kaA.x * SCALE_L2E, kaA.y * SCALE_L2E),
                                   pack2bf(kaA.z * SCALE_L2E, kaA.w * SCALE_L2E));
    *(uint2*)&Vws[oA] = make_uint2(pack2bf(vaA.x, vaA.y), pack2bf(vaA.z, vaA.w));
    *(uint2*)&Kws[oB] = make_uint2(pack2bf(kaB.x * SCALE_L2E, kaB.y * SCALE_L2E),
                                   pack2bf(kaB.z * SCALE_L2E, kaB.w * SCALE_L2E));
    *(uint2*)&Vws[oB] = make_uint2(pack2bf(vaB.x, vaB.y), pack2bf(vaB.z, vaB.w));
}

// ---------------------------------------------------------------------------
// Kernel 2: MFMA flash attention, double-buffered (byte-identical to R7/R8).
//   S^T = K * Q^T ; P = exp2(S^T) (fixed max) ; O^T = V^T * P^T ;
//   Dsum = ones * P^T  (denominator; every reg = sum over keys for q=lane&15)
// V^T staged with per-32-chunk column permutation pos(Q,t',r) <- key(t',Q,r)
// so B-operand k-slot 8Q+j pairs with C-layout reg (t'=j>=4, r=j&3) of quad Q.
// ---------------------------------------------------------------------------
__global__ __launch_bounds__(256, 4) void attn_kernel(
    const float* __restrict__ query,
    const u16* __restrict__ Kws, const u16* __restrict__ Vws,
    float* __restrict__ out)
{
    __shared__ __align__(16) u16 Klds[2][KT][40];       // 2 x 10.0 KB
    __shared__ __align__(16) u16 Vtlds[2][HD][KT + 8];  // 2 x 8.5 KB

    const int tid  = threadIdx.x;
    const int lane = tid & 63;
    const int wv   = tid >> 6;
    const int q15  = lane & 15;
    const int quad = lane >> 4;

    const int blk = blockIdx.x;        // 1024 = 128 bh * 8 qtiles
    const int bh  = blk >> 3;
    const int qt  = blk & 7;
    const int b = bh >> 3, h = bh & 7;
    const int q0w = qt * 128 + wv * 32;  // wave's first query

    // ---- Q fragments: 2 x (16 rows x 32 d), fp32 global -> bf16 regs ----
    short8 qf[2];
    #pragma unroll
    for (int f = 0; f < 2; f++) {
        const float* qp = query + ((size_t)(b * S_ + q0w + f * 16 + q15)) * CC
                          + h * HD + quad * 8;
        float4 a = *(const float4*)(qp);
        float4 c = *(const float4*)(qp + 4);
        short8 v;
        v[0] = (short)f2bf(a.x); v[1] = (short)f2bf(a.y);
        v[2] = (short)f2bf(a.z); v[3] = (short)f2bf(a.w);
        v[4] = (short)f2bf(c.x); v[5] = (short)f2bf(c.y);
        v[6] = (short)f2bf(c.z); v[7] = (short)f2bf(c.w);
        qf[f] = v;
    }

    short8 ones;                       // bf16 1.0 = 0x3F80
    #pragma unroll
    for (int j = 0; j < 8; j++) ones[j] = (short)0x3F80;

    const u16* Kg = Kws + (size_t)bh * S_ * HD;
    const u16* Vg = Vws + (size_t)bh * S_ * HD;

    // ---- staging geometry (fixed per thread) ----
    const int krow = tid >> 1, khalf = tid & 1;
    const int vg  = tid >> 3, vs4 = tid & 7;
    const int vc = vg >> 3, vw = vg & 7;
    const int vt2 = (vw >> 2) & 1, vqd = vw & 3;
    const int vpg = (vc << 5) | (vqd << 3) | (vt2 << 2);   // permuted col base

    uint4 kra, krb;                    // K stage regs (32 B/thread)
    uint2 vr0, vr1, vr2, vr3;          // V stage regs (32 B/thread)

    auto issue_loads = [&](int kt0) {
        const uint4* ksrc = (const uint4*)(Kg + (size_t)(kt0 + krow) * HD + khalf * 16);
        kra = ksrc[0]; krb = ksrc[1];
        const uint2* vsrc = (const uint2*)(Vg + (size_t)(kt0 + 4 * vg) * HD + 4 * vs4);
        vr0 = vsrc[0]; vr1 = vsrc[8]; vr2 = vsrc[16]; vr3 = vsrc[24];
    };
    auto write_lds = [&](int p) {
        uint4* kdst = (uint4*)&Klds[p][krow][khalf * 16];
        kdst[0] = kra; kdst[1] = krb;
        u32 a, bb;
        a  = __builtin_amdgcn_perm(vr1.x, vr0.x, 0x05040100u);
        bb = __builtin_amdgcn_perm(vr3.x, vr2.x, 0x05040100u);
        *(uint2*)&Vtlds[p][4 * vs4 + 0][vpg] = make_uint2(a, bb);
        a  = __builtin_amdgcn_perm(vr1.x, vr0.x, 0x07060302u);
        bb = __builtin_amdgcn_perm(vr3.x, vr2.x, 0x07060302u);
        *(uint2*)&Vtlds[p][4 * vs4 + 1][vpg] = make_uint2(a, bb);
        a  = __builtin_amdgcn_perm(vr1.y, vr0.y, 0x05040100u);
        bb = __builtin_amdgcn_perm(vr3.y, vr2.y, 0x05040100u);
        *(uint2*)&Vtlds[p][4 * vs4 + 2][vpg] = make_uint2(a, bb);
        a  = __builtin_amdgcn_perm(vr1.y, vr0.y, 0x07060302u);
        bb = __builtin_amdgcn_perm(vr3.y, vr2.y, 0x07060302u);
        *(uint2*)&Vtlds[p][4 * vs4 + 3][vpg] = make_uint2(a, bb);
    };

    f32x4 Ot[2][2];                    // [frag][dhalf], C-layout (rows = d)
    f32x4 Dsum[2];                     // denominator accumulator
    #pragma unroll
    for (int f = 0; f < 2; f++) {
        Ot[f][0] = (f32x4)0.f; Ot[f][1] = (f32x4)0.f; Dsum[f] = (f32x4)0.f;
    }

    issue_loads(0);
    write_lds(0);                      // prologue: buffer 0

    for (int it = 0; it < NITER; it++) {
        const int p = it & 1;
        if (it + 1 < NITER) issue_loads((it + 1) * KT);   // in flight across barrier+compute
        __syncthreads();               // buf p writes visible; prev readers of buf 1-p done

        // ---- chunk-fused: QK -> exp2 -> pack -> PV per 32 keys ----
        #pragma unroll
        for (int c = 0; c < 4; c++) {
            short8 kf0 = *(const short8*)&Klds[p][c * 32 + q15][quad * 8];
            short8 kf1 = *(const short8*)&Klds[p][c * 32 + 16 + q15][quad * 8];
            short8 vf0 = *(const short8*)&Vtlds[p][q15][c * 32 + quad * 8];
            short8 vf1 = *(const short8*)&Vtlds[p][16 + q15][c * 32 + quad * 8];
            #pragma unroll
            for (int f = 0; f < 2; f++) {
                f32x4 s0 = __builtin_amdgcn_mfma_f32_16x16x32_bf16(kf0, qf[f], (f32x4)0.f, 0, 0, 0);
                f32x4 s1 = __builtin_amdgcn_mfma_f32_16x16x32_bf16(kf1, qf[f], (f32x4)0.f, 0, 0, 0);
                #pragma unroll
                for (int r = 0; r < 4; r++) {
                    s0[r] = __builtin_amdgcn_exp2f(s0[r]);
                    s1[r] = __builtin_amdgcn_exp2f(s1[r]);
                }
                union { u32 u[4]; short8 s8; } pk;   // bf16-truncate pack
                pk.u[0] = __builtin_amdgcn_perm(__float_as_uint(s0[1]),
                                                __float_as_uint(s0[0]), 0x07060302u);
                pk.u[1] = __builtin_amdgcn_perm(__float_as_uint(s0[3]),
                                                __float_as_uint(s0[2]), 0x07060302u);
                pk.u[2] = __builtin_amdgcn_perm(__float_as_uint(s1[1]),
                                                __float_as_uint(s1[0]), 0x07060302u);
                pk.u[3] = __builtin_amdgcn_perm(__float_as_uint(s1[3]),
                                                __float_as_uint(s1[2]), 0x07060302u);
                Ot[f][0] = __builtin_amdgcn_mfma_f32_16x16x32_bf16(vf0, pk.s8, Ot[f][0], 0, 0, 0);
                Ot[f][1] = __builtin_amdgcn_mfma_f32_16x16x32_bf16(vf1, pk.s8, Ot[f][1], 0, 0, 0);
                Dsum[f]  = __builtin_amdgcn_mfma_f32_16x16x32_bf16(ones, pk.s8, Dsum[f], 0, 0, 0);
            }
        }
        if (it + 1 < NITER) write_lds((it + 1) & 1);      // idle buffer; next barrier publishes
    }

    // ---- epilogue: O^T[d][q] / Dsum[q] -> out[b][q][h*32+d] ----
    #pragma unroll
    for (int f = 0; f < 2; f++) {
        float inv = 1.0f / Dsum[f][0];
        int qg = q0w + f * 16 + q15;
        float* op = out + ((size_t)(b * S_ + qg)) * CC + h * HD;
        #pragma unroll
        for (int h2 = 0; h2 < 2; h2++)
            #pragma unroll
            for (int r = 0; r < 4; r++)
                op[h2 * 16 + quad * 4 + r] = Ot[f][h2][r] * inv;
    }
}

// ---------------------------------------------------------------------------
extern "C" void kernel_launch(void* const* d_in, const int* in_sizes, int n_in,
                              void* d_out, int out_size, void* d_ws, size_t ws_size,
                              hipStream_t stream)
{
    const float* query  = (const float*)d_in[0];
    const float* key_in = (const float*)d_in[1];
    const float* value  = (const float*)d_in[2];
    const float* ck     = (const float*)d_in[3];
    const float* cb     = (const float*)d_in[4];
    float* out = (float*)d_out;

    u16* Kws = (u16*)d_ws;
    u16* Vws = Kws + (size_t)B_ * HEADS * S_ * HD;

    // 4 channels x 2 y-pixels per thread: grid = 16*16*32*64 / 256 = 2048 blocks.
    dw_conv_kernel<<<(B_ * 16 * WW * (CC / 4)) / 256, 256, 0, stream>>>(
        key_in, value, ck, cb, Kws, Vws);

    // 128 queries per block (4 waves x 32): grid = 131072/128 = 1024 blocks.
    attn_kernel<<<(B_ * HEADS * S_) / 128, 256, 0, stream>>>(
        query, Kws, Vws, out);
}